// Round 4
// baseline (1270.893 us; speedup 1.0000x reference)
//
#include <hip/hip_runtime.h>

// ReLU15 (Tsallis alpha=1.5) loss, fused single-pass streaming reduction.
//
// loss = (1/N) * sum_i [ (sum_j p - sum_j p^1.5)/0.75 + <p - onehot(t_i), X_i - 2*tau> ]
// with p_j = relu(0.5*x_j - tau)^2 = r^2, so sqrt(p)=r exactly and the whole
// thing reduces to:
//   per-element contrib: p * (4/3 + x - 2*tau - (4/3)*r)
//   per-row correction:  -(X[i, t_i] - 2*tau)
// One flat reduction over 262.1M floats + 8192 gathers. Memory-bound:
// 1.048 GB single read -> ~166us floor at 6.3 TB/s achievable.

#define TAU         0.05f
#define N_ROWS      8192
#define NUM_CLASSES 32000

constexpr int BLOCK = 256;
constexpr int GRID  = 2048;   // 8 blocks/CU x 4 waves = 32 waves/CU (max TLP)

// target dtype is ambiguous at the ABI boundary (reference says int64; the
// harness convention says int32; JAX without x64 silently downcasts).
// Discriminate at runtime: view the first 8 elements as int64 — int64 data
// always lands in [0, NUM_CLASSES); int32 data viewed as int64 has a nonzero
// high word with prob 1 - (1/32000)^8 ~= 1. Reads 64B (safe for either
// layout), wave-uniform branch, identical work every call (graph-safe).
__device__ inline long long load_target(const void* tgt, long long row)
{
    const long long* t64 = (const long long*)tgt;
    bool is64 = true;
    #pragma unroll
    for (int k = 0; k < 8; ++k) {
        long long v = t64[k];
        if (v < 0 || v >= NUM_CLASSES) is64 = false;
    }
    return is64 ? t64[row] : (long long)((const int*)tgt)[row];
}

__global__ __launch_bounds__(BLOCK)
void relu15_main_kernel(const float* __restrict__ X,
                        const void* __restrict__ target,
                        float* __restrict__ block_partials,
                        long long n4)
{
    const long long tid    = (long long)blockIdx.x * BLOCK + threadIdx.x;
    const long long stride = (long long)GRID * BLOCK;

    const float4* __restrict__ X4 = reinterpret_cast<const float4*>(X);

    const float C0 = 4.0f / 3.0f - 2.0f * TAU;   // 4/3 + (x - 2tau) = x + C0
    const float C1 = -4.0f / 3.0f;

    // 4 independent accumulators (one per float4 lane-slot): kills the only
    // per-thread dependence chain so the loop is purely memory-issue-limited.
    float acc0 = 0.0f, acc1 = 0.0f, acc2 = 0.0f, acc3 = 0.0f;
    for (long long i = tid; i < n4; i += stride) {
        float4 v = X4[i];
        {
            float r = fmaxf(fmaf(0.5f, v.x, -TAU), 0.0f);
            acc0 = fmaf(r * r, fmaf(C1, r, v.x + C0), acc0);
        }
        {
            float r = fmaxf(fmaf(0.5f, v.y, -TAU), 0.0f);
            acc1 = fmaf(r * r, fmaf(C1, r, v.y + C0), acc1);
        }
        {
            float r = fmaxf(fmaf(0.5f, v.z, -TAU), 0.0f);
            acc2 = fmaf(r * r, fmaf(C1, r, v.z + C0), acc2);
        }
        {
            float r = fmaxf(fmaf(0.5f, v.w, -TAU), 0.0f);
            acc3 = fmaf(r * r, fmaf(C1, r, v.w + C0), acc3);
        }
    }
    float acc = (acc0 + acc1) + (acc2 + acc3);

    // Per-row gather correction: -(X[row, target[row]] - 2*tau), one per row,
    // spread across the first N_ROWS global threads (~1MB of scattered
    // cachelines total; negligible vs the 1GB stream).
    if (tid < N_ROWS) {
        long long t = load_target(target, tid);
        acc -= X[tid * (long long)NUM_CLASSES + t] - 2.0f * TAU;
    }

    // Wave (64-lane) shuffle reduction
    #pragma unroll
    for (int off = 32; off > 0; off >>= 1)
        acc += __shfl_down(acc, off, 64);

    __shared__ float wave_sums[BLOCK / 64];
    const int lane = threadIdx.x & 63;
    const int wid  = threadIdx.x >> 6;
    if (lane == 0) wave_sums[wid] = acc;
    __syncthreads();

    if (threadIdx.x == 0) {
        float s = wave_sums[0] + wave_sums[1] + wave_sums[2] + wave_sums[3];
        block_partials[blockIdx.x] = s;
    }
}

__global__ __launch_bounds__(BLOCK)
void relu15_final_kernel(const float* __restrict__ block_partials,
                         float* __restrict__ out,
                         int n_partials)
{
    double acc = 0.0;
    for (int i = threadIdx.x; i < n_partials; i += BLOCK)
        acc += (double)block_partials[i];

    #pragma unroll
    for (int off = 32; off > 0; off >>= 1)
        acc += __shfl_down(acc, off, 64);

    __shared__ double wave_sums[BLOCK / 64];
    const int lane = threadIdx.x & 63;
    const int wid  = threadIdx.x >> 6;
    if (lane == 0) wave_sums[wid] = acc;
    __syncthreads();

    if (threadIdx.x == 0) {
        double s = wave_sums[0] + wave_sums[1] + wave_sums[2] + wave_sums[3];
        out[0] = (float)(s / (double)N_ROWS);
    }
}

extern "C" void kernel_launch(void* const* d_in, const int* in_sizes, int n_in,
                              void* d_out, int out_size, void* d_ws, size_t ws_size,
                              hipStream_t stream)
{
    const float* X        = (const float*)d_in[0];
    const void*  target   = d_in[1];
    float*       out      = (float*)d_out;
    float*       partials = (float*)d_ws;   // GRID floats = 8 KB scratch

    const long long n_elems = (long long)in_sizes[0];   // 8192*32000 = 262,144,000
    const long long n4      = n_elems / 4;              // divisible by 4

    relu15_main_kernel<<<GRID, BLOCK, 0, stream>>>(X, target, partials, n4);
    relu15_final_kernel<<<1, BLOCK, 0, stream>>>(partials, out, GRID);
}